// Round 1
// 807.506 us; speedup vs baseline: 2.0930x; 2.0930x over previous
//
#include <hip/hip_runtime.h>

#define B_    2
#define S_    2048
#define D_    1024
#define H_    16
#define DH_   64
#define BH_   (B_ * H_)          // 32
#define SCALE_ 0.125f

typedef __attribute__((ext_vector_type(8))) _Float16 f16x8;
typedef __attribute__((ext_vector_type(4))) float    f32x4;

#define MFMA16(a, b, c) __builtin_amdgcn_mfma_f32_16x16x32_f16((a), (b), (c), 0, 0, 0)

// LDS 16B-chunk XOR swizzles: spread MFMA fragment reads (16 lanes walking rows
// at fixed chunk) across banks. Applied identically on write and read, so the
// mapping is self-consistent (both-sides-or-neither rule).
#define SWZ64(r, c)  ((r) * 64  + ((((c) ^ (((r) >> 1) & 3))) << 4))  // 32-half rows
#define SWZ128(r, c) ((r) * 128 + ((((c) ^ ((r) & 7))) << 4))         // 64-half rows

// ---------------------------------------------------------------------------
// One launch: cast q,k,v (4M elems each) + Wq,Wk,Wv,Wo (1M each) fp32 -> fp16
// into a contiguous ws region (same segment order). 2097152 vec8 total.
// ---------------------------------------------------------------------------
__global__ __launch_bounds__(256)
void cast_all_kernel(const float* __restrict__ q, const float* __restrict__ k,
                     const float* __restrict__ v, const float* __restrict__ wq,
                     const float* __restrict__ wk, const float* __restrict__ wv,
                     const float* __restrict__ wo, _Float16* __restrict__ dst)
{
    const size_t gid = (size_t)blockIdx.x * 256 + threadIdx.x;   // vec8 index
    const size_t M4 = (size_t)B_ * S_ * D_ / 8;                  // 524288
    const size_t M1 = (size_t)D_ * D_ / 8;                       // 131072
    const float* src;
    size_t off;
    if (gid < 3 * M4) {
        const size_t seg = gid / M4;
        off = gid - seg * M4;
        src = (seg == 0) ? q : (seg == 1 ? k : v);
    } else {
        const size_t g2  = gid - 3 * M4;
        const size_t seg = g2 / M1;
        off = g2 - seg * M1;
        src = (seg == 0) ? wq : (seg == 1 ? wk : (seg == 2 ? wv : wo));
    }
    const float4 a = ((const float4*)src)[off * 2 + 0];
    const float4 b = ((const float4*)src)[off * 2 + 1];
    union { f16x8 h; float4 f; } u;
    u.h[0] = (_Float16)a.x; u.h[1] = (_Float16)a.y;
    u.h[2] = (_Float16)a.z; u.h[3] = (_Float16)a.w;
    u.h[4] = (_Float16)b.x; u.h[5] = (_Float16)b.y;
    u.h[6] = (_Float16)b.z; u.h[7] = (_Float16)b.w;
    ((float4*)dst)[gid] = u.f;
}

// ---------------------------------------------------------------------------
// MFMA projection: Y = (A @ W^T + bias) * outscale
//   A [M=4096, K=1024] f16 row-major, W [N=1024, K=1024] f16 row-major (B^T GEMM)
//   head_layout=1 -> fp16 Y[((b*H+h)*S+s)*Dh+d] ; head_layout=0 -> fp32 Y[m*D+n]
// BM=128 BN=64 BK=32, 256 threads = 4 waves stacked on M (32 rows x 64 cols each).
// ---------------------------------------------------------------------------
__global__ __launch_bounds__(256)
void proj_f16_kernel(const _Float16* __restrict__ A, const _Float16* __restrict__ W,
                     const float* __restrict__ bias, void* __restrict__ Y,
                     const int head_layout, const float outscale)
{
    __shared__ __align__(16) char As[128 * 64];  // 128 rows x 32 halves (swizzled)
    __shared__ __align__(16) char Bs[64 * 64];   // 64 rows x 32 halves

    const int t   = threadIdx.x;
    const int w   = t >> 6;
    const int l   = t & 63;
    const int llo = l & 15, lhi = l >> 4;
    const int row0 = blockIdx.x * 128;
    const int col0 = blockIdx.y * 64;

    const int sr = t >> 2;   // staged row 0..63
    const int sc = t & 3;    // 16B chunk in 32-half row
    const _Float16* Ap0 = A + (size_t)(row0 + sr) * D_ + sc * 8;
    const _Float16* Ap1 = A + (size_t)(row0 + 64 + sr) * D_ + sc * 8;
    const _Float16* Bp  = W + (size_t)(col0 + sr) * D_ + sc * 8;
    const int lwa0 = SWZ64(sr, sc);
    const int lwa1 = SWZ64(64 + sr, sc);
    const int lwb  = SWZ64(sr, sc);

    const f32x4 z4 = {0.f, 0.f, 0.f, 0.f};
    f32x4 acc[2][4];
    #pragma unroll
    for (int mi = 0; mi < 2; ++mi)
        #pragma unroll
        for (int ni = 0; ni < 4; ++ni) acc[mi][ni] = z4;

    float4 pa0 = *(const float4*)Ap0;
    float4 pa1 = *(const float4*)Ap1;
    float4 pb0 = *(const float4*)Bp;

    for (int k0 = 0; k0 < D_; k0 += 32) {
        __syncthreads();                     // prior iter's frag reads done
        *(float4*)(As + lwa0) = pa0;
        *(float4*)(As + lwa1) = pa1;
        *(float4*)(Bs + lwb)  = pb0;
        if (k0 + 32 < D_) {                  // prefetch next tile (hides HBM under MFMA)
            pa0 = *(const float4*)(Ap0 + k0 + 32);
            pa1 = *(const float4*)(Ap1 + k0 + 32);
            pb0 = *(const float4*)(Bp  + k0 + 32);
        }
        __syncthreads();
        f16x8 av[2], bv[4];
        #pragma unroll
        for (int mi = 0; mi < 2; ++mi) {
            const int r = w * 32 + mi * 16 + llo;
            av[mi] = *(const f16x8*)(As + SWZ64(r, lhi));
        }
        #pragma unroll
        for (int ni = 0; ni < 4; ++ni) {
            const int r = ni * 16 + llo;
            bv[ni] = *(const f16x8*)(Bs + SWZ64(r, lhi));
        }
        #pragma unroll
        for (int mi = 0; mi < 2; ++mi)
            #pragma unroll
            for (int ni = 0; ni < 4; ++ni)
                acc[mi][ni] = MFMA16(av[mi], bv[ni], acc[mi][ni]);
    }

    // epilogue: C/D layout col = lane&15, row = (lane>>4)*4 + j  [m89-verified]
    #pragma unroll
    for (int ni = 0; ni < 4; ++ni) {
        const int n = col0 + ni * 16 + llo;
        const float bn = bias[n];
        #pragma unroll
        for (int mi = 0; mi < 2; ++mi) {
            #pragma unroll
            for (int j = 0; j < 4; ++j) {
                const int m = row0 + w * 32 + mi * 16 + lhi * 4 + j;
                const float val = (acc[mi][ni][j] + bn) * outscale;
                if (head_layout) {
                    ((_Float16*)Y)[(((size_t)(m >> 11) * H_ + (n >> 6)) * S_
                                    + (m & (S_ - 1))) * DH_ + (n & 63)] = (_Float16)val;
                } else {
                    ((float*)Y)[(size_t)m * D_ + n] = val;
                }
            }
        }
    }
}

// ---------------------------------------------------------------------------
// V head transpose: Vt[bh][d][s] = Vh[bh][s][d]  (PV's B-operand needs
// k-contiguous reads; one cheap 16 MB pass beats per-tile scatter staging)
// ---------------------------------------------------------------------------
__global__ __launch_bounds__(256)
void transpose_v_kernel(const _Float16* __restrict__ Vh, _Float16* __restrict__ Vt)
{
    __shared__ __align__(16) _Float16 T[64][72];   // +8 pad breaks column-read conflicts
    const int t  = threadIdx.x;
    const int k0 = blockIdx.x * 64;
    const int bh = blockIdx.y;
    const _Float16* src = Vh + (size_t)bh * S_ * DH_;
    _Float16* dst = Vt + (size_t)bh * DH_ * S_;

    #pragma unroll
    for (int i = 0; i < 2; ++i) {
        const int r = i * 32 + (t >> 3);
        const int c = t & 7;
        *(float4*)&T[r][c * 8] = *(const float4*)&src[(size_t)(k0 + r) * DH_ + c * 8];
    }
    __syncthreads();
    #pragma unroll
    for (int i = 0; i < 2; ++i) {
        const int d = i * 32 + (t >> 3);
        const int c = t & 7;
        union { f16x8 h; float4 f; } u;
        #pragma unroll
        for (int jj = 0; jj < 8; ++jj) u.h[jj] = T[c * 8 + jj][d];
        *(float4*)&dst[(size_t)d * S_ + k0 + c * 8] = u.f;
    }
}

// ---------------------------------------------------------------------------
// Fused scores + softmax + attn-write + PV. One block = (bh, 64 q-rows).
// Pass 1: QK^T via MFMA, online row max/sum (no score storage).
// Pass 2: recompute scores (bit-identical), p = exp(s-m)/sum -> write fp32 attn
//         (the ONLY attn HBM traffic), push p as fp16 through LDS, PV MFMA.
// 4 waves; wave w owns q-rows [w*16, w*16+16). LDS 32 KB -> ~4 blocks/CU.
// ---------------------------------------------------------------------------
__global__ __launch_bounds__(256)
void attn_fused_kernel(const _Float16* __restrict__ Qh, const _Float16* __restrict__ Kh,
                       const _Float16* __restrict__ Vt, float* __restrict__ attn,
                       _Float16* __restrict__ oh)
{
    __shared__ __align__(16) char Qs[8192], Ks[8192], Vs[8192], Ps[8192];
    const int t   = threadIdx.x;
    const int w   = t >> 6;
    const int l   = t & 63;
    const int llo = l & 15, lhi = l >> 4;
    const int q0  = blockIdx.x * 64;
    const int bh  = blockIdx.y;
    const _Float16* Qb = Qh + (size_t)bh * S_ * DH_;
    const _Float16* Kb = Kh + (size_t)bh * S_ * DH_;
    const _Float16* Vb = Vt + (size_t)bh * DH_ * S_;

    const int sr  = t >> 3;                 // staged row 0..31
    const int sc  = t & 7;                  // 16B chunk in 64-half row
    const int lw0 = SWZ128(sr, sc);
    const int lw1 = SWZ128(32 + sr, sc);

    // ---- stage Q tile (64 x 64 halves), then Q frags live in regs ----
    *(float4*)(Qs + lw0) = *(const float4*)&Qb[(size_t)(q0 + sr) * DH_ + sc * 8];
    *(float4*)(Qs + lw1) = *(const float4*)&Qb[(size_t)(q0 + 32 + sr) * DH_ + sc * 8];
    __syncthreads();
    f16x8 aq[2];
    {
        const int r = w * 16 + llo;
        aq[0] = *(const f16x8*)(Qs + SWZ128(r, lhi));
        aq[1] = *(const f16x8*)(Qs + SWZ128(r, 4 + lhi));
    }

    float mrun[4], srun[4];
    #pragma unroll
    for (int j = 0; j < 4; ++j) { mrun[j] = -1e30f; srun[j] = 0.f; }

    // ---- pass 1 ----
    float4 kp0 = *(const float4*)&Kb[(size_t)sr * DH_ + sc * 8];
    float4 kp1 = *(const float4*)&Kb[(size_t)(32 + sr) * DH_ + sc * 8];
    for (int t0 = 0; t0 < S_ / 64; ++t0) {
        __syncthreads();
        *(float4*)(Ks + lw0) = kp0;
        *(float4*)(Ks + lw1) = kp1;
        if (t0 + 1 < S_ / 64) {
            kp0 = *(const float4*)&Kb[(size_t)((t0 + 1) * 64 + sr) * DH_ + sc * 8];
            kp1 = *(const float4*)&Kb[(size_t)((t0 + 1) * 64 + 32 + sr) * DH_ + sc * 8];
        }
        __syncthreads();
        f32x4 acc[4];
        #pragma unroll
        for (int fn = 0; fn < 4; ++fn) {
            const int r = fn * 16 + llo;
            const f16x8 b0 = *(const f16x8*)(Ks + SWZ128(r, lhi));
            const f16x8 b1 = *(const f16x8*)(Ks + SWZ128(r, 4 + lhi));
            f32x4 a = {0.f, 0.f, 0.f, 0.f};
            a = MFMA16(aq[0], b0, a);
            a = MFMA16(aq[1], b1, a);
            acc[fn] = a;
        }
        // online max/sum; row j of this lane-group reduces over its 16 lanes
        #pragma unroll
        for (int j = 0; j < 4; ++j) {
            float tm = fmaxf(fmaxf(acc[0][j], acc[1][j]), fmaxf(acc[2][j], acc[3][j]));
            #pragma unroll
            for (int o = 1; o < 16; o <<= 1) tm = fmaxf(tm, __shfl_xor(tm, o));
            const float mn = fmaxf(mrun[j], tm);
            float ts = __expf(acc[0][j] - mn) + __expf(acc[1][j] - mn)
                     + __expf(acc[2][j] - mn) + __expf(acc[3][j] - mn);
            #pragma unroll
            for (int o = 1; o < 16; o <<= 1) ts += __shfl_xor(ts, o);
            srun[j] = srun[j] * __expf(mrun[j] - mn) + ts;
            mrun[j] = mn;
        }
    }
    float inv[4];
    #pragma unroll
    for (int j = 0; j < 4; ++j) inv[j] = 1.0f / srun[j];

    // ---- pass 2 ----
    const f32x4 z4 = {0.f, 0.f, 0.f, 0.f};
    f32x4 oacc[4];
    #pragma unroll
    for (int dn = 0; dn < 4; ++dn) oacc[dn] = z4;

    kp0 = *(const float4*)&Kb[(size_t)sr * DH_ + sc * 8];
    kp1 = *(const float4*)&Kb[(size_t)(32 + sr) * DH_ + sc * 8];
    float4 vp0 = *(const float4*)&Vb[(size_t)sr * S_ + sc * 8];
    float4 vp1 = *(const float4*)&Vb[(size_t)(32 + sr) * S_ + sc * 8];
    float* attnBase = attn + (size_t)bh * S_ * S_
                    + (size_t)(q0 + w * 16 + lhi * 4) * S_ + llo;

    for (int t0 = 0; t0 < S_ / 64; ++t0) {
        __syncthreads();                    // prior iter's PV frag reads done
        *(float4*)(Ks + lw0) = kp0;
        *(float4*)(Ks + lw1) = kp1;
        *(float4*)(Vs + lw0) = vp0;
        *(float4*)(Vs + lw1) = vp1;
        if (t0 + 1 < S_ / 64) {
            kp0 = *(const float4*)&Kb[(size_t)((t0 + 1) * 64 + sr) * DH_ + sc * 8];
            kp1 = *(const float4*)&Kb[(size_t)((t0 + 1) * 64 + 32 + sr) * DH_ + sc * 8];
            vp0 = *(const float4*)&Vb[(size_t)sr * S_ + (t0 + 1) * 64 + sc * 8];
            vp1 = *(const float4*)&Vb[(size_t)(32 + sr) * S_ + (t0 + 1) * 64 + sc * 8];
        }
        __syncthreads();
        f32x4 acc[4];
        #pragma unroll
        for (int fn = 0; fn < 4; ++fn) {
            const int r = fn * 16 + llo;
            const f16x8 b0 = *(const f16x8*)(Ks + SWZ128(r, lhi));
            const f16x8 b1 = *(const f16x8*)(Ks + SWZ128(r, 4 + lhi));
            f32x4 a = {0.f, 0.f, 0.f, 0.f};
            a = MFMA16(aq[0], b0, a);
            a = MFMA16(aq[1], b1, a);
            acc[fn] = a;
        }
        // p = exp(s - m_final) * inv_sum : exact normalized attn (no O-rescale needed)
        const int pr = w * 16 + lhi * 4;
        #pragma unroll
        for (int fn = 0; fn < 4; ++fn) {
            const int pc = fn * 16 + llo;
            #pragma unroll
            for (int j = 0; j < 4; ++j) {
                const float p = __expf(acc[fn][j] - mrun[j]) * inv[j];
                attnBase[(size_t)j * S_ + t0 * 64 + fn * 16] = p;
                const int prj = pr + j;
                *(_Float16*)(Ps + prj * 128 + ((((pc >> 3) ^ (prj & 7))) << 4)
                             + (pc & 7) * 2) = (_Float16)p;
            }
        }
        __syncthreads();                    // Ps visible
        #pragma unroll
        for (int ks = 0; ks < 2; ++ks) {
            const f16x8 pa = *(const f16x8*)(Ps + SWZ128(w * 16 + llo, ks * 4 + lhi));
            #pragma unroll
            for (int dn = 0; dn < 4; ++dn) {
                const f16x8 bv = *(const f16x8*)(Vs + SWZ128(dn * 16 + llo, ks * 4 + lhi));
                oacc[dn] = MFMA16(pa, bv, oacc[dn]);
            }
        }
    }

    const int b = bh >> 4, h = bh & 15;
    #pragma unroll
    for (int dn = 0; dn < 4; ++dn) {
        #pragma unroll
        for (int j = 0; j < 4; ++j) {
            const int qrow = q0 + w * 16 + lhi * 4 + j;
            oh[((size_t)b * S_ + qrow) * D_ + h * DH_ + dn * 16 + llo] = (_Float16)oacc[dn][j];
        }
    }
}

// ---------------------------------------------------------------------------
extern "C" void kernel_launch(void* const* d_in, const int* in_sizes, int n_in,
                              void* d_out, int out_size, void* d_ws, size_t ws_size,
                              hipStream_t stream)
{
    const float* q  = (const float*)d_in[0];
    const float* k  = (const float*)d_in[1];
    const float* v  = (const float*)d_in[2];
    const float* Wq = (const float*)d_in[3];
    const float* bq = (const float*)d_in[4];
    const float* Wk = (const float*)d_in[5];
    const float* bk = (const float*)d_in[6];
    const float* Wv = (const float*)d_in[7];
    const float* bv = (const float*)d_in[8];
    const float* Wo = (const float*)d_in[9];
    const float* bo = (const float*)d_in[10];

    float* out  = (float*)d_out;                     // [B,S,D]
    float* attn = out + (size_t)B_ * S_ * D_;        // [B,H,S,S]

    // ws layout (halves). Peak 56 MB (< 64 MB used by prior version).
    _Float16* ws  = (_Float16*)d_ws;
    _Float16* qh  = ws;                              // 4M  (input q fp16)
    _Float16* kh  = qh  + 4194304;                   // 4M
    _Float16* vh  = kh  + 4194304;                   // 4M
    _Float16* wqh = vh  + 4194304;                   // 1M
    _Float16* wkh = wqh + 1048576;
    _Float16* wvh = wkh + 1048576;
    _Float16* woh = wvh + 1048576;
    _Float16* Qh  = woh + 1048576;                   // 4M [B,H,S,Dh] (pre-scaled by 0.125)
    _Float16* Kh  = Qh  + 4194304;                   // 4M
    _Float16* Vh  = Kh  + 4194304;                   // 4M
    _Float16* Vt  = qh;   // alias: qh dead after Q projection
    _Float16* oh  = kh;   // alias: kh dead after K projection

    cast_all_kernel<<<8192, 256, 0, stream>>>(q, k, v, Wq, Wk, Wv, Wo, ws);

    const dim3 gproj(32, 16);   // M/128 x N/64
    proj_f16_kernel<<<gproj, 256, 0, stream>>>(qh, wqh, bq, Qh, 1, SCALE_);
    proj_f16_kernel<<<gproj, 256, 0, stream>>>(kh, wkh, bk, Kh, 1, 1.0f);
    proj_f16_kernel<<<gproj, 256, 0, stream>>>(vh, wvh, bv, Vh, 1, 1.0f);

    transpose_v_kernel<<<dim3(S_ / 64, BH_), 256, 0, stream>>>(Vh, Vt);
    attn_fused_kernel<<<dim3(S_ / 64, BH_), 256, 0, stream>>>(Qh, Kh, Vt, attn, oh);

    proj_f16_kernel<<<gproj, 256, 0, stream>>>(oh, woh, bo, out, 0, 1.0f);
}